// Round 15
// baseline (160.437 us; speedup 1.0000x reference)
//
#include <hip/hip_runtime.h>

// Problem dims (hardcoded from reference)
#define T_STEPS 100
#define B_N     128
#define IN_F    512
#define OUT_F   512

// fp64 decay constants: exp(-DT/TAU_*)
#define ALPHA_D 0.8187307530779818   // exp(-1/5)   synaptic
#define BETA_D  0.9512294245007140   // exp(-1/20)  membrane

typedef __attribute__((ext_vector_type(8))) short bf16x8;
typedef __attribute__((ext_vector_type(4))) float f32x4;

static __device__ __forceinline__ unsigned int f2bf(float f) {
    union { float f; unsigned int u; } v; v.f = f;
    return (v.u + 0x7FFFu + ((v.u >> 16) & 1u)) >> 16;   // RNE
}

// expand 8 binary bits -> 8 bf16 (1.0 / 0.0), packed 2-per-u32
static __device__ __forceinline__ bf16x8 expand8(unsigned int byte) {
    union { unsigned int u[4]; bf16x8 v; } r;
#pragma unroll
    for (int p = 0; p < 4; ++p) {
        r.u[p] = (((byte >> (2 * p)) & 1u) ? 0x3F80u : 0u) |
                 (((byte >> (2 * p + 1)) & 1u) ? 0x3F800000u : 0u);
    }
    return r.v;
}

// ---------------------------------------------------------------------------
// K1: transpose W (OUT x IN) -> Wt (IN x OUT).  (ws[0 .. 1MB))
// ---------------------------------------------------------------------------
__global__ __launch_bounds__(256) void transposeW(const float* __restrict__ W,
                                                  float* __restrict__ Wt) {
    __shared__ float tile[32][33];
    const int bx = blockIdx.x & 15;   // i-tile
    const int by = blockIdx.x >> 4;   // o-tile
    const int tx = threadIdx.x & 31;
    const int ty = threadIdx.x >> 5;  // 0..7
#pragma unroll
    for (int k = 0; k < 32; k += 8) {
        int o = by * 32 + ty + k;
        tile[ty + k][tx] = W[o * IN_F + bx * 32 + tx];
    }
    __syncthreads();
#pragma unroll
    for (int k = 0; k < 32; k += 8) {
        int i = bx * 32 + ty + k;
        Wt[i * OUT_F + by * 32 + tx] = tile[tx][ty + k];
    }
}

// ---------------------------------------------------------------------------
// K2: fused grid.
// Blocks [0, 512): pack x into bitmask Xbits[b][i] = 128 bits over t (1 MB).
// Blocks [512, 512+12800): synaptic current C[t,b,o] in fp64.
// R15: gather vectorized — thread covers o = {2*tid, 2*tid+1} via float2
// loads (one wave-instruction per 2KB row instead of two; half the address
// VALU), k-loop unrolled 2x -> 4 independent loads in flight. Fixed-order
// fp64 chain combine (even-k + odd-k) keeps determinism; C written as one
// coalesced double2.
// ---------------------------------------------------------------------------
__global__ __launch_bounds__(256) void syn_plus(const float* __restrict__ x,
                                                const float* __restrict__ Wt,
                                                double* __restrict__ C,
                                                unsigned int* __restrict__ Xbits) {
    const int tid = threadIdx.x;

    if ((int)blockIdx.x < 512) {
        // ---- x_to_bits: block covers (b, i-quarter of 128) ----
        const int b    = blockIdx.x >> 2;
        const int q    = blockIdx.x & 3;
        const int half = tid >> 7;            // 0: t<64 (words 0,1), 1: t>=64 (2,3)
        const int i    = q * 128 + (tid & 127);
        const float* xc = x + (size_t)b * IN_F + i;
        unsigned int wA = 0u, wB = 0u;
        if (half == 0) {
#pragma unroll
            for (int tt = 0; tt < 32; ++tt)
                wA |= (xc[(size_t)tt * (B_N * IN_F)] > 0.5f ? 1u : 0u) << tt;
#pragma unroll
            for (int tt = 0; tt < 32; ++tt)
                wB |= (xc[(size_t)(32 + tt) * (B_N * IN_F)] > 0.5f ? 1u : 0u) << tt;
        } else {
#pragma unroll
            for (int tt = 0; tt < 32; ++tt)
                wA |= (xc[(size_t)(64 + tt) * (B_N * IN_F)] > 0.5f ? 1u : 0u) << tt;
#pragma unroll
            for (int tt = 0; tt < 4; ++tt)    // t = 96..99; 100..127 stay 0
                wB |= (xc[(size_t)(96 + tt) * (B_N * IN_F)] > 0.5f ? 1u : 0u) << tt;
        }
        ((uint2*)Xbits)[(size_t)(b * IN_F + i) * 2 + half] = make_uint2(wA, wB);
        return;
    }

    // ---- syn_current ----
    const int tb = (int)blockIdx.x - 512;     // t*B + b

    __shared__ int s_idx[IN_F];
    __shared__ int s_cnt;

    if (tid < 64) {                      // wave 0 builds ascending active list
        const float* xr = x + (size_t)tb * IN_F;
        int base = 0;
#pragma unroll
        for (int j = 0; j < 8; ++j) {
            const float v = xr[j * 64 + tid];
            const unsigned long long m = __ballot(v > 0.5f);
            if (v > 0.5f) {
                const int pos = base + __popcll(m & ((1ull << tid) - 1ull));
                s_idx[pos] = j * 64 + tid;
            }
            base += __popcll(m);
        }
        if (tid == 0) s_cnt = base;
    }
    __syncthreads();

    const int cnt = s_cnt;
    const float2* W2 = (const float2*)Wt + tid;   // row i: W2[i*256]
    double c0 = 0.0, c1 = 0.0, c2 = 0.0, c3 = 0.0;
    int k = 0;
    for (; k + 1 < cnt; k += 2) {        // 2 rows/iter, 4 indep fp64 chains
        const int i0 = s_idx[k];
        const int i1 = s_idx[k + 1];
        const float2 va = W2[(size_t)i0 * 256];
        const float2 vb = W2[(size_t)i1 * 256];
        c0 += (double)va.x; c1 += (double)va.y;
        c2 += (double)vb.x; c3 += (double)vb.y;
    }
    if (k < cnt) {
        const float2 va = W2[(size_t)s_idx[k] * 256];
        c0 += (double)va.x; c1 += (double)va.y;
    }

    double2* Cr = (double2*)(C + (size_t)tb * OUT_F) + tid;
    *Cr = make_double2(c0 + c2, c1 + c3);    // o = 2*tid, 2*tid+1
}

// ---------------------------------------------------------------------------
// K_B: elementwise LIF scan (R4-proven). fp64 recurrence, double-buffered
// 10-step chunks, static indices only.
// ---------------------------------------------------------------------------
#define LIF_STEP(BUF, J, CB)                                                   \
    {                                                                          \
        const int t = (CB) * 10 + (J);                                         \
        I = ALPHA_D * I + BUF[J];                                              \
        U = BETA_D * U + I;                                                    \
        const double Sv = (U >= 1.0) ? 1.0 : 0.0;                              \
        S_out[(size_t)t * N + pos] = (float)Sv;                                \
        Uh[(size_t)(2 * t) * N + pos] = (float)U;                              \
        U -= Sv;                                                               \
        Uh[(size_t)(2 * t + 1) * N + pos] = (float)U;                          \
        U -= Sv;                                                               \
    }

__global__ __launch_bounds__(256) void lif_pointwise(const double* __restrict__ C,
                                                     float* __restrict__ S_out,
                                                     float* __restrict__ Uh) {
    const int pos = blockIdx.x * 256 + threadIdx.x;   // b*OUT + o
    const size_t N = (size_t)B_N * OUT_F;

    double I = 0.0, U = 0.0;
    double bufA[10], bufB[10];

#pragma unroll
    for (int j = 0; j < 10; ++j) bufA[j] = C[(size_t)j * N + pos];

    for (int cb = 0; cb < 10; cb += 2) {
#pragma unroll
        for (int j = 0; j < 10; ++j) bufB[j] = C[((size_t)(cb + 1) * 10 + j) * N + pos];
#pragma unroll
        for (int j = 0; j < 10; ++j) LIF_STEP(bufA, j, cb)
        if (cb + 2 < 10) {
#pragma unroll
            for (int j = 0; j < 10; ++j) bufA[j] = C[((size_t)(cb + 2) * 10 + j) * N + pos];
        }
#pragma unroll
        for (int j = 0; j < 10; ++j) LIF_STEP(bufB, j, cb + 1)
    }
}

// ---------------------------------------------------------------------------
// K3: trace[b] = P^T @ X; X fabricated in registers from the 1 MB bitmask.
// (R14-proven: LDS union Psm/obuf, 17.4 KB -> 8 blocks/CU; f32x4 nt epilogue)
// ---------------------------------------------------------------------------
__global__ __launch_bounds__(256) void trace_bits3(const float* __restrict__ Uh,
                                                   const unsigned int* __restrict__ Xbits,
                                                   float* __restrict__ trace) {
    __shared__ char smem[17408];
    char*  const Psm  = smem;            // [64 o][256B k] bf16 swz (staging only)
    float* const obuf = (float*)smem;    // [64][68] f32 (after hoist)

    const int tid = threadIdx.x;
    const int b   = blockIdx.x & 127;    // b%8 spreads XCDs
    const int ot  = blockIdx.x >> 7;     // 0..7 (64-o panel)

    // ---- stage P panel: 64 o x 128 k (t>=100 -> 0) ----
    {
        const int o_l = tid & 63;
        const int cg  = tid >> 6;        // 4 chunks per thread
        const float* up = Uh + (size_t)b * OUT_F + ot * 64 + o_l;
#pragma unroll
        for (int cc = 0; cc < 4; ++cc) {
            const int c = cg * 4 + cc;   // 16B chunk = 8 t
            unsigned int h[4];
#pragma unroll
            for (int jj = 0; jj < 4; ++jj) {
                unsigned int hw[2];
#pragma unroll
                for (int e = 0; e < 2; ++e) {
                    const int t = c * 8 + jj * 2 + e;
                    float p = 0.f;
                    if (t < T_STEPS) {
                        const float u  = up[(size_t)(2 * t + 1) * (B_N * OUT_F)];
                        const float du = fabsf(u - 1.0f);
                        const float dd = 1.0f + 0.03f * du;
                        p = __expf(-0.05f * (float)(T_STEPS - 1 - t)) / (dd * dd);
                    }
                    hw[e] = f2bf(p);
                }
                h[jj] = hw[0] | (hw[1] << 16);
            }
            const unsigned loff = (unsigned)(o_l * 256) +
                (((unsigned)(c * 16)) ^ (((unsigned)(o_l & 7)) << 4));
            *(uint4*)(Psm + loff) = make_uint4(h[0], h[1], h[2], h[3]);
        }
    }
    __syncthreads();

    // ---- hoist A-fragments (wave w owns o rows [w*16, w*16+16)) ----
    const int w = tid >> 6, l = tid & 63, lo16 = l & 15, g4 = l >> 4;
    bf16x8 af[4];
    {
        const int row = w * 16 + lo16;
#pragma unroll
        for (int kk = 0; kk < 4; ++kk) {
            const unsigned off = (unsigned)(row * 256 + kk * 64 + g4 * 16)
                                 ^ ((unsigned)(row & 7) << 4);
            af[kk] = *(const bf16x8*)(Psm + off);
        }
    }
    __syncthreads();                     // Psm dead; obuf may now use the space

    float* const tb = trace + (size_t)b * (OUT_F * IN_F) + (size_t)(ot * 64) * IN_F;
    const uint4* const xb = (const uint4*)Xbits + (size_t)b * IN_F;  // one uint4 / i
    const int sh = g4 * 8;

    for (int it = 0; it < 8; ++it) {
        // bit-words for this lane's 4 B-columns (i = it*64 + n*16 + lo16)
        uint4 xw[4];
#pragma unroll
        for (int n = 0; n < 4; ++n) xw[n] = xb[it * 64 + n * 16 + lo16];

        f32x4 acc[4];
#pragma unroll
        for (int n = 0; n < 4; ++n) acc[n] = (f32x4){0.f, 0.f, 0.f, 0.f};

#pragma unroll
        for (int kk = 0; kk < 4; ++kk) {
#pragma unroll
            for (int n = 0; n < 4; ++n) {
                const unsigned int word = ((const unsigned int*)&xw[n])[kk];
                const bf16x8 bfr = expand8((word >> sh) & 0xFFu);
                acc[n] = __builtin_amdgcn_mfma_f32_16x16x32_bf16(af[kk], bfr, acc[n], 0, 0, 0);
            }
        }

        // ---- epilogue: acc -> obuf (stride-68 pad) -> f32x4 nt stores ----
#pragma unroll
        for (int n = 0; n < 4; ++n)
#pragma unroll
            for (int rr = 0; rr < 4; ++rr)
                obuf[(w * 16 + g4 * 4 + rr) * 68 + n * 16 + lo16] = acc[n][rr];
        __syncthreads();

#pragma unroll
        for (int p = 0; p < 4; ++p) {
            const int row  = p * 16 + (tid >> 4);   // 0..63
            const int col4 = (tid & 15) * 4;        // 0..60
            const f32x4 v = *(const f32x4*)&obuf[row * 68 + col4];
            __builtin_nontemporal_store(v,
                (f32x4*)(tb + (size_t)row * IN_F + it * 64 + col4));
        }
        __syncthreads();                 // obuf reads done before next overwrite
    }
}

// ---------------------------------------------------------------------------
extern "C" void kernel_launch(void* const* d_in, const int* in_sizes, int n_in,
                              void* d_out, int out_size, void* d_ws, size_t ws_size,
                              hipStream_t stream) {
    const float* x = (const float*)d_in[0];   // (T, B, IN) binary spikes
    const float* W = (const float*)d_in[1];   // (OUT, IN)

    float* out   = (float*)d_out;
    float* S_out = out;                                            // (T, B, OUT)
    float* Uh    = out + (size_t)T_STEPS * B_N * OUT_F;            // (2T, B, OUT)
    float* trace = Uh + (size_t)2 * T_STEPS * B_N * OUT_F;         // (B, OUT, IN)

    // ws layout: Wt (1 MB) | Xbits (1 MB). ws >= 3.2 MB proven (R9/R10 ran).
    float*        Wt    = (float*)d_ws;
    unsigned int* Xbits = (unsigned int*)((char*)d_ws + (size_t)IN_F * OUT_F * 4);

    // C (f64, 52 MB) reuses the trace region of d_out; trace_bits3 reads only
    // Uh + Xbits and runs last, so no hazard.
    double* C = (double*)trace;

    transposeW<<<256, 256, 0, stream>>>(W, Wt);
    syn_plus<<<512 + T_STEPS * B_N, 256, 0, stream>>>(x, Wt, C, Xbits);
    lif_pointwise<<<B_N * OUT_F / 256, 256, 0, stream>>>(C, S_out, Uh);
    trace_bits3<<<1024, 256, 0, stream>>>(Uh, Xbits, trace);
}

// Round 16
// 136.712 us; speedup vs baseline: 1.1735x; 1.1735x over previous
//
#include <hip/hip_runtime.h>

// Problem dims (hardcoded from reference)
#define T_STEPS 100
#define B_N     128
#define IN_F    512
#define OUT_F   512

// fp64 decay constants: exp(-DT/TAU_*)
#define ALPHA_D 0.8187307530779818   // exp(-1/5)   synaptic
#define BETA_D  0.9512294245007140   // exp(-1/20)  membrane

typedef __attribute__((ext_vector_type(8))) short bf16x8;
typedef __attribute__((ext_vector_type(4))) float f32x4;

static __device__ __forceinline__ unsigned int f2bf(float f) {
    union { float f; unsigned int u; } v; v.f = f;
    return (v.u + 0x7FFFu + ((v.u >> 16) & 1u)) >> 16;   // RNE
}

// expand 8 binary bits -> 8 bf16 (1.0 / 0.0), packed 2-per-u32
static __device__ __forceinline__ bf16x8 expand8(unsigned int byte) {
    union { unsigned int u[4]; bf16x8 v; } r;
#pragma unroll
    for (int p = 0; p < 4; ++p) {
        r.u[p] = (((byte >> (2 * p)) & 1u) ? 0x3F80u : 0u) |
                 (((byte >> (2 * p + 1)) & 1u) ? 0x3F800000u : 0u);
    }
    return r.v;
}

// ---------------------------------------------------------------------------
// K1: transpose W (OUT x IN) -> Wt (IN x OUT).  (ws[0 .. 1MB))
// ---------------------------------------------------------------------------
__global__ __launch_bounds__(256) void transposeW(const float* __restrict__ W,
                                                  float* __restrict__ Wt) {
    __shared__ float tile[32][33];
    const int bx = blockIdx.x & 15;   // i-tile
    const int by = blockIdx.x >> 4;   // o-tile
    const int tx = threadIdx.x & 31;
    const int ty = threadIdx.x >> 5;  // 0..7
#pragma unroll
    for (int k = 0; k < 32; k += 8) {
        int o = by * 32 + ty + k;
        tile[ty + k][tx] = W[o * IN_F + bx * 32 + tx];
    }
    __syncthreads();
#pragma unroll
    for (int k = 0; k < 32; k += 8) {
        int i = bx * 32 + ty + k;
        Wt[i * OUT_F + by * 32 + tx] = tile[tx][ty + k];
    }
}

// ---------------------------------------------------------------------------
// K2: fused grid.
// Blocks [0, 512): pack x into bitmask Xbits[b][i] = 128 bits over t (1 MB).
// Blocks [512, 512+12800): synaptic current C[t,b,o] in fp64 via
//   ballot-compacted active list + uniform gather over L2-resident Wt.
// R16: gather = R14-proven SCALAR dword loads (R15's float2 regressed 30us —
// load shape matters, not just byte count), but with 2x k-unroll: 4
// independent fp64 chains / 4 loads in flight. Fixed combine order.
// ---------------------------------------------------------------------------
__global__ __launch_bounds__(256) void syn_plus(const float* __restrict__ x,
                                                const float* __restrict__ Wt,
                                                double* __restrict__ C,
                                                unsigned int* __restrict__ Xbits) {
    const int tid = threadIdx.x;

    if ((int)blockIdx.x < 512) {
        // ---- x_to_bits: block covers (b, i-quarter of 128) ----
        const int b    = blockIdx.x >> 2;
        const int q    = blockIdx.x & 3;
        const int half = tid >> 7;            // 0: t<64 (words 0,1), 1: t>=64 (2,3)
        const int i    = q * 128 + (tid & 127);
        const float* xc = x + (size_t)b * IN_F + i;
        unsigned int wA = 0u, wB = 0u;
        if (half == 0) {
#pragma unroll
            for (int tt = 0; tt < 32; ++tt)
                wA |= (xc[(size_t)tt * (B_N * IN_F)] > 0.5f ? 1u : 0u) << tt;
#pragma unroll
            for (int tt = 0; tt < 32; ++tt)
                wB |= (xc[(size_t)(32 + tt) * (B_N * IN_F)] > 0.5f ? 1u : 0u) << tt;
        } else {
#pragma unroll
            for (int tt = 0; tt < 32; ++tt)
                wA |= (xc[(size_t)(64 + tt) * (B_N * IN_F)] > 0.5f ? 1u : 0u) << tt;
#pragma unroll
            for (int tt = 0; tt < 4; ++tt)    // t = 96..99; 100..127 stay 0
                wB |= (xc[(size_t)(96 + tt) * (B_N * IN_F)] > 0.5f ? 1u : 0u) << tt;
        }
        ((uint2*)Xbits)[(size_t)(b * IN_F + i) * 2 + half] = make_uint2(wA, wB);
        return;
    }

    // ---- syn_current ----
    const int tb = (int)blockIdx.x - 512;     // t*B + b

    __shared__ int s_idx[IN_F];
    __shared__ int s_cnt;

    if (tid < 64) {                      // wave 0 builds ascending active list
        const float* xr = x + (size_t)tb * IN_F;
        int base = 0;
#pragma unroll
        for (int j = 0; j < 8; ++j) {
            const float v = xr[j * 64 + tid];
            const unsigned long long m = __ballot(v > 0.5f);
            if (v > 0.5f) {
                const int pos = base + __popcll(m & ((1ull << tid) - 1ull));
                s_idx[pos] = j * 64 + tid;
            }
            base += __popcll(m);
        }
        if (tid == 0) s_cnt = base;
    }
    __syncthreads();

    const int cnt = s_cnt;
    const float* W0 = Wt + tid;
    const float* W1 = Wt + tid + 256;
    double c0 = 0.0, c1 = 0.0, c2 = 0.0, c3 = 0.0;
    int k = 0;
    for (; k + 1 < cnt; k += 2) {        // scalar dword loads, 4 indep chains
        const int i0 = s_idx[k];
        const int i1 = s_idx[k + 1];
        c0 += (double)W0[(size_t)i0 * OUT_F];
        c1 += (double)W1[(size_t)i0 * OUT_F];
        c2 += (double)W0[(size_t)i1 * OUT_F];
        c3 += (double)W1[(size_t)i1 * OUT_F];
    }
    if (k < cnt) {
        const int i0 = s_idx[k];
        c0 += (double)W0[(size_t)i0 * OUT_F];
        c1 += (double)W1[(size_t)i0 * OUT_F];
    }

    double* Cr = C + (size_t)tb * OUT_F;
    Cr[tid]       = c0 + c2;             // fixed combine order
    Cr[tid + 256] = c1 + c3;
}

// ---------------------------------------------------------------------------
// K_B: elementwise LIF scan (R4-proven). fp64 recurrence, double-buffered
// 10-step chunks, static indices only.
// ---------------------------------------------------------------------------
#define LIF_STEP(BUF, J, CB)                                                   \
    {                                                                          \
        const int t = (CB) * 10 + (J);                                         \
        I = ALPHA_D * I + BUF[J];                                              \
        U = BETA_D * U + I;                                                    \
        const double Sv = (U >= 1.0) ? 1.0 : 0.0;                              \
        S_out[(size_t)t * N + pos] = (float)Sv;                                \
        Uh[(size_t)(2 * t) * N + pos] = (float)U;                              \
        U -= Sv;                                                               \
        Uh[(size_t)(2 * t + 1) * N + pos] = (float)U;                          \
        U -= Sv;                                                               \
    }

__global__ __launch_bounds__(256) void lif_pointwise(const double* __restrict__ C,
                                                     float* __restrict__ S_out,
                                                     float* __restrict__ Uh) {
    const int pos = blockIdx.x * 256 + threadIdx.x;   // b*OUT + o
    const size_t N = (size_t)B_N * OUT_F;

    double I = 0.0, U = 0.0;
    double bufA[10], bufB[10];

#pragma unroll
    for (int j = 0; j < 10; ++j) bufA[j] = C[(size_t)j * N + pos];

    for (int cb = 0; cb < 10; cb += 2) {
#pragma unroll
        for (int j = 0; j < 10; ++j) bufB[j] = C[((size_t)(cb + 1) * 10 + j) * N + pos];
#pragma unroll
        for (int j = 0; j < 10; ++j) LIF_STEP(bufA, j, cb)
        if (cb + 2 < 10) {
#pragma unroll
            for (int j = 0; j < 10; ++j) bufA[j] = C[((size_t)(cb + 2) * 10 + j) * N + pos];
        }
#pragma unroll
        for (int j = 0; j < 10; ++j) LIF_STEP(bufB, j, cb + 1)
    }
}

// ---------------------------------------------------------------------------
// K3: trace[b] = P^T @ X; X fabricated in registers from the 1 MB bitmask.
// (R14-proven: LDS union Psm/obuf, 17.4 KB -> 8 blocks/CU; f32x4 nt epilogue)
// ---------------------------------------------------------------------------
__global__ __launch_bounds__(256) void trace_bits3(const float* __restrict__ Uh,
                                                   const unsigned int* __restrict__ Xbits,
                                                   float* __restrict__ trace) {
    __shared__ char smem[17408];
    char*  const Psm  = smem;            // [64 o][256B k] bf16 swz (staging only)
    float* const obuf = (float*)smem;    // [64][68] f32 (after hoist)

    const int tid = threadIdx.x;
    const int b   = blockIdx.x & 127;    // b%8 spreads XCDs
    const int ot  = blockIdx.x >> 7;     // 0..7 (64-o panel)

    // ---- stage P panel: 64 o x 128 k (t>=100 -> 0) ----
    {
        const int o_l = tid & 63;
        const int cg  = tid >> 6;        // 4 chunks per thread
        const float* up = Uh + (size_t)b * OUT_F + ot * 64 + o_l;
#pragma unroll
        for (int cc = 0; cc < 4; ++cc) {
            const int c = cg * 4 + cc;   // 16B chunk = 8 t
            unsigned int h[4];
#pragma unroll
            for (int jj = 0; jj < 4; ++jj) {
                unsigned int hw[2];
#pragma unroll
                for (int e = 0; e < 2; ++e) {
                    const int t = c * 8 + jj * 2 + e;
                    float p = 0.f;
                    if (t < T_STEPS) {
                        const float u  = up[(size_t)(2 * t + 1) * (B_N * OUT_F)];
                        const float du = fabsf(u - 1.0f);
                        const float dd = 1.0f + 0.03f * du;
                        p = __expf(-0.05f * (float)(T_STEPS - 1 - t)) / (dd * dd);
                    }
                    hw[e] = f2bf(p);
                }
                h[jj] = hw[0] | (hw[1] << 16);
            }
            const unsigned loff = (unsigned)(o_l * 256) +
                (((unsigned)(c * 16)) ^ (((unsigned)(o_l & 7)) << 4));
            *(uint4*)(Psm + loff) = make_uint4(h[0], h[1], h[2], h[3]);
        }
    }
    __syncthreads();

    // ---- hoist A-fragments (wave w owns o rows [w*16, w*16+16)) ----
    const int w = tid >> 6, l = tid & 63, lo16 = l & 15, g4 = l >> 4;
    bf16x8 af[4];
    {
        const int row = w * 16 + lo16;
#pragma unroll
        for (int kk = 0; kk < 4; ++kk) {
            const unsigned off = (unsigned)(row * 256 + kk * 64 + g4 * 16)
                                 ^ ((unsigned)(row & 7) << 4);
            af[kk] = *(const bf16x8*)(Psm + off);
        }
    }
    __syncthreads();                     // Psm dead; obuf may now use the space

    float* const tb = trace + (size_t)b * (OUT_F * IN_F) + (size_t)(ot * 64) * IN_F;
    const uint4* const xb = (const uint4*)Xbits + (size_t)b * IN_F;  // one uint4 / i
    const int sh = g4 * 8;

    for (int it = 0; it < 8; ++it) {
        // bit-words for this lane's 4 B-columns (i = it*64 + n*16 + lo16)
        uint4 xw[4];
#pragma unroll
        for (int n = 0; n < 4; ++n) xw[n] = xb[it * 64 + n * 16 + lo16];

        f32x4 acc[4];
#pragma unroll
        for (int n = 0; n < 4; ++n) acc[n] = (f32x4){0.f, 0.f, 0.f, 0.f};

#pragma unroll
        for (int kk = 0; kk < 4; ++kk) {
#pragma unroll
            for (int n = 0; n < 4; ++n) {
                const unsigned int word = ((const unsigned int*)&xw[n])[kk];
                const bf16x8 bfr = expand8((word >> sh) & 0xFFu);
                acc[n] = __builtin_amdgcn_mfma_f32_16x16x32_bf16(af[kk], bfr, acc[n], 0, 0, 0);
            }
        }

        // ---- epilogue: acc -> obuf (stride-68 pad) -> f32x4 nt stores ----
#pragma unroll
        for (int n = 0; n < 4; ++n)
#pragma unroll
            for (int rr = 0; rr < 4; ++rr)
                obuf[(w * 16 + g4 * 4 + rr) * 68 + n * 16 + lo16] = acc[n][rr];
        __syncthreads();

#pragma unroll
        for (int p = 0; p < 4; ++p) {
            const int row  = p * 16 + (tid >> 4);   // 0..63
            const int col4 = (tid & 15) * 4;        // 0..60
            const f32x4 v = *(const f32x4*)&obuf[row * 68 + col4];
            __builtin_nontemporal_store(v,
                (f32x4*)(tb + (size_t)row * IN_F + it * 64 + col4));
        }
        __syncthreads();                 // obuf reads done before next overwrite
    }
}

// ---------------------------------------------------------------------------
extern "C" void kernel_launch(void* const* d_in, const int* in_sizes, int n_in,
                              void* d_out, int out_size, void* d_ws, size_t ws_size,
                              hipStream_t stream) {
    const float* x = (const float*)d_in[0];   // (T, B, IN) binary spikes
    const float* W = (const float*)d_in[1];   // (OUT, IN)

    float* out   = (float*)d_out;
    float* S_out = out;                                            // (T, B, OUT)
    float* Uh    = out + (size_t)T_STEPS * B_N * OUT_F;            // (2T, B, OUT)
    float* trace = Uh + (size_t)2 * T_STEPS * B_N * OUT_F;         // (B, OUT, IN)

    // ws layout: Wt (1 MB) | Xbits (1 MB). ws >= 3.2 MB proven (R9/R10 ran).
    float*        Wt    = (float*)d_ws;
    unsigned int* Xbits = (unsigned int*)((char*)d_ws + (size_t)IN_F * OUT_F * 4);

    // C (f64, 52 MB) reuses the trace region of d_out; trace_bits3 reads only
    // Uh + Xbits and runs last, so no hazard.
    double* C = (double*)trace;

    transposeW<<<256, 256, 0, stream>>>(W, Wt);
    syn_plus<<<512 + T_STEPS * B_N, 256, 0, stream>>>(x, Wt, C, Xbits);
    lif_pointwise<<<B_N * OUT_F / 256, 256, 0, stream>>>(C, S_out, Uh);
    trace_bits3<<<1024, 256, 0, stream>>>(Uh, Xbits, trace);
}

// Round 17
// 129.966 us; speedup vs baseline: 1.2345x; 1.0519x over previous
//
#include <hip/hip_runtime.h>

// Problem dims (hardcoded from reference)
#define T_STEPS 100
#define B_N     128
#define IN_F    512
#define OUT_F   512

// fp64 decay constants: exp(-DT/TAU_*)
#define ALPHA_D 0.8187307530779818   // exp(-1/5)   synaptic
#define BETA_D  0.9512294245007140   // exp(-1/20)  membrane

typedef __attribute__((ext_vector_type(8))) short bf16x8;
typedef __attribute__((ext_vector_type(4))) float f32x4;

static __device__ __forceinline__ unsigned int f2bf(float f) {
    union { float f; unsigned int u; } v; v.f = f;
    return (v.u + 0x7FFFu + ((v.u >> 16) & 1u)) >> 16;   // RNE
}

// expand 8 binary bits -> 8 bf16 (1.0 / 0.0), packed 2-per-u32
static __device__ __forceinline__ bf16x8 expand8(unsigned int byte) {
    union { unsigned int u[4]; bf16x8 v; } r;
#pragma unroll
    for (int p = 0; p < 4; ++p) {
        r.u[p] = (((byte >> (2 * p)) & 1u) ? 0x3F80u : 0u) |
                 (((byte >> (2 * p + 1)) & 1u) ? 0x3F800000u : 0u);
    }
    return r.v;
}

// ---------------------------------------------------------------------------
// K1: transpose W (OUT x IN) -> Wt (IN x OUT).  (ws[0 .. 1MB))
// ---------------------------------------------------------------------------
__global__ __launch_bounds__(256) void transposeW(const float* __restrict__ W,
                                                  float* __restrict__ Wt) {
    __shared__ float tile[32][33];
    const int bx = blockIdx.x & 15;   // i-tile
    const int by = blockIdx.x >> 4;   // o-tile
    const int tx = threadIdx.x & 31;
    const int ty = threadIdx.x >> 5;  // 0..7
#pragma unroll
    for (int k = 0; k < 32; k += 8) {
        int o = by * 32 + ty + k;
        tile[ty + k][tx] = W[o * IN_F + bx * 32 + tx];
    }
    __syncthreads();
#pragma unroll
    for (int k = 0; k < 32; k += 8) {
        int i = bx * 32 + ty + k;
        Wt[i * OUT_F + by * 32 + tx] = tile[tx][ty + k];
    }
}

// ---------------------------------------------------------------------------
// K2: fused grid.
// Blocks [0, 512): pack x into bitmask Xbits[b][i] = 128 bits over t (1 MB).
// Blocks [512, 512+12800): synaptic current C[t,b,o] in fp64 via
//   ballot-compacted active list + uniform gather over L2-resident Wt.
// Gather = R14-proven simple scalar-dword loop (R15 float2 and R16 unroll
// both regressed — this simple form is the empirical optimum).
// ---------------------------------------------------------------------------
__global__ __launch_bounds__(256) void syn_plus(const float* __restrict__ x,
                                                const float* __restrict__ Wt,
                                                double* __restrict__ C,
                                                unsigned int* __restrict__ Xbits) {
    const int tid = threadIdx.x;

    if ((int)blockIdx.x < 512) {
        // ---- x_to_bits: block covers (b, i-quarter of 128) ----
        const int b    = blockIdx.x >> 2;
        const int q    = blockIdx.x & 3;
        const int half = tid >> 7;            // 0: t<64 (words 0,1), 1: t>=64 (2,3)
        const int i    = q * 128 + (tid & 127);
        const float* xc = x + (size_t)b * IN_F + i;
        unsigned int wA = 0u, wB = 0u;
        if (half == 0) {
#pragma unroll
            for (int tt = 0; tt < 32; ++tt)
                wA |= (xc[(size_t)tt * (B_N * IN_F)] > 0.5f ? 1u : 0u) << tt;
#pragma unroll
            for (int tt = 0; tt < 32; ++tt)
                wB |= (xc[(size_t)(32 + tt) * (B_N * IN_F)] > 0.5f ? 1u : 0u) << tt;
        } else {
#pragma unroll
            for (int tt = 0; tt < 32; ++tt)
                wA |= (xc[(size_t)(64 + tt) * (B_N * IN_F)] > 0.5f ? 1u : 0u) << tt;
#pragma unroll
            for (int tt = 0; tt < 4; ++tt)    // t = 96..99; 100..127 stay 0
                wB |= (xc[(size_t)(96 + tt) * (B_N * IN_F)] > 0.5f ? 1u : 0u) << tt;
        }
        ((uint2*)Xbits)[(size_t)(b * IN_F + i) * 2 + half] = make_uint2(wA, wB);
        return;
    }

    // ---- syn_current ----
    const int tb = (int)blockIdx.x - 512;     // t*B + b

    __shared__ int s_idx[IN_F];
    __shared__ int s_cnt;

    if (tid < 64) {                      // wave 0 builds ascending active list
        const float* xr = x + (size_t)tb * IN_F;
        int base = 0;
#pragma unroll
        for (int j = 0; j < 8; ++j) {
            const float v = xr[j * 64 + tid];
            const unsigned long long m = __ballot(v > 0.5f);
            if (v > 0.5f) {
                const int pos = base + __popcll(m & ((1ull << tid) - 1ull));
                s_idx[pos] = j * 64 + tid;
            }
            base += __popcll(m);
        }
        if (tid == 0) s_cnt = base;
    }
    __syncthreads();

    const int cnt = s_cnt;
    double c0 = 0.0, c1 = 0.0;
    const float* W0 = Wt + tid;
    const float* W1 = Wt + tid + 256;
    for (int k = 0; k < cnt; ++k) {
        const int i = s_idx[k];          // LDS broadcast (uniform address)
        c0 += (double)W0[(size_t)i * OUT_F];
        c1 += (double)W1[(size_t)i * OUT_F];
    }

    double* Cr = C + (size_t)tb * OUT_F;
    Cr[tid]       = c0;
    Cr[tid + 256] = c1;
}

// ---------------------------------------------------------------------------
// K_B: elementwise LIF scan (R4-proven). fp64 recurrence, double-buffered
// 10-step chunks, static indices only.
// ---------------------------------------------------------------------------
#define LIF_STEP(BUF, J, CB)                                                   \
    {                                                                          \
        const int t = (CB) * 10 + (J);                                         \
        I = ALPHA_D * I + BUF[J];                                              \
        U = BETA_D * U + I;                                                    \
        const double Sv = (U >= 1.0) ? 1.0 : 0.0;                              \
        S_out[(size_t)t * N + pos] = (float)Sv;                                \
        Uh[(size_t)(2 * t) * N + pos] = (float)U;                              \
        U -= Sv;                                                               \
        Uh[(size_t)(2 * t + 1) * N + pos] = (float)U;                          \
        U -= Sv;                                                               \
    }

__global__ __launch_bounds__(256) void lif_pointwise(const double* __restrict__ C,
                                                     float* __restrict__ S_out,
                                                     float* __restrict__ Uh) {
    const int pos = blockIdx.x * 256 + threadIdx.x;   // b*OUT + o
    const size_t N = (size_t)B_N * OUT_F;

    double I = 0.0, U = 0.0;
    double bufA[10], bufB[10];

#pragma unroll
    for (int j = 0; j < 10; ++j) bufA[j] = C[(size_t)j * N + pos];

    for (int cb = 0; cb < 10; cb += 2) {
#pragma unroll
        for (int j = 0; j < 10; ++j) bufB[j] = C[((size_t)(cb + 1) * 10 + j) * N + pos];
#pragma unroll
        for (int j = 0; j < 10; ++j) LIF_STEP(bufA, j, cb)
        if (cb + 2 < 10) {
#pragma unroll
            for (int j = 0; j < 10; ++j) bufA[j] = C[((size_t)(cb + 2) * 10 + j) * N + pos];
        }
#pragma unroll
        for (int j = 0; j < 10; ++j) LIF_STEP(bufB, j, cb + 1)
    }
}

// ---------------------------------------------------------------------------
// K3: trace[b] = P^T @ X; X fabricated in registers from the 1 MB bitmask.
// (R14-proven: LDS union Psm/obuf, 17.4 KB -> 8 blocks/CU; f32x4 nt epilogue)
// ---------------------------------------------------------------------------
__global__ __launch_bounds__(256) void trace_bits3(const float* __restrict__ Uh,
                                                   const unsigned int* __restrict__ Xbits,
                                                   float* __restrict__ trace) {
    __shared__ char smem[17408];
    char*  const Psm  = smem;            // [64 o][256B k] bf16 swz (staging only)
    float* const obuf = (float*)smem;    // [64][68] f32 (after hoist)

    const int tid = threadIdx.x;
    const int b   = blockIdx.x & 127;    // b%8 spreads XCDs
    const int ot  = blockIdx.x >> 7;     // 0..7 (64-o panel)

    // ---- stage P panel: 64 o x 128 k (t>=100 -> 0) ----
    {
        const int o_l = tid & 63;
        const int cg  = tid >> 6;        // 4 chunks per thread
        const float* up = Uh + (size_t)b * OUT_F + ot * 64 + o_l;
#pragma unroll
        for (int cc = 0; cc < 4; ++cc) {
            const int c = cg * 4 + cc;   // 16B chunk = 8 t
            unsigned int h[4];
#pragma unroll
            for (int jj = 0; jj < 4; ++jj) {
                unsigned int hw[2];
#pragma unroll
                for (int e = 0; e < 2; ++e) {
                    const int t = c * 8 + jj * 2 + e;
                    float p = 0.f;
                    if (t < T_STEPS) {
                        const float u  = up[(size_t)(2 * t + 1) * (B_N * OUT_F)];
                        const float du = fabsf(u - 1.0f);
                        const float dd = 1.0f + 0.03f * du;
                        p = __expf(-0.05f * (float)(T_STEPS - 1 - t)) / (dd * dd);
                    }
                    hw[e] = f2bf(p);
                }
                h[jj] = hw[0] | (hw[1] << 16);
            }
            const unsigned loff = (unsigned)(o_l * 256) +
                (((unsigned)(c * 16)) ^ (((unsigned)(o_l & 7)) << 4));
            *(uint4*)(Psm + loff) = make_uint4(h[0], h[1], h[2], h[3]);
        }
    }
    __syncthreads();

    // ---- hoist A-fragments (wave w owns o rows [w*16, w*16+16)) ----
    const int w = tid >> 6, l = tid & 63, lo16 = l & 15, g4 = l >> 4;
    bf16x8 af[4];
    {
        const int row = w * 16 + lo16;
#pragma unroll
        for (int kk = 0; kk < 4; ++kk) {
            const unsigned off = (unsigned)(row * 256 + kk * 64 + g4 * 16)
                                 ^ ((unsigned)(row & 7) << 4);
            af[kk] = *(const bf16x8*)(Psm + off);
        }
    }
    __syncthreads();                     // Psm dead; obuf may now use the space

    float* const tb = trace + (size_t)b * (OUT_F * IN_F) + (size_t)(ot * 64) * IN_F;
    const uint4* const xb = (const uint4*)Xbits + (size_t)b * IN_F;  // one uint4 / i
    const int sh = g4 * 8;

    for (int it = 0; it < 8; ++it) {
        // bit-words for this lane's 4 B-columns (i = it*64 + n*16 + lo16)
        uint4 xw[4];
#pragma unroll
        for (int n = 0; n < 4; ++n) xw[n] = xb[it * 64 + n * 16 + lo16];

        f32x4 acc[4];
#pragma unroll
        for (int n = 0; n < 4; ++n) acc[n] = (f32x4){0.f, 0.f, 0.f, 0.f};

#pragma unroll
        for (int kk = 0; kk < 4; ++kk) {
#pragma unroll
            for (int n = 0; n < 4; ++n) {
                const unsigned int word = ((const unsigned int*)&xw[n])[kk];
                const bf16x8 bfr = expand8((word >> sh) & 0xFFu);
                acc[n] = __builtin_amdgcn_mfma_f32_16x16x32_bf16(af[kk], bfr, acc[n], 0, 0, 0);
            }
        }

        // ---- epilogue: acc -> obuf (stride-68 pad) -> f32x4 nt stores ----
#pragma unroll
        for (int n = 0; n < 4; ++n)
#pragma unroll
            for (int rr = 0; rr < 4; ++rr)
                obuf[(w * 16 + g4 * 4 + rr) * 68 + n * 16 + lo16] = acc[n][rr];
        __syncthreads();

#pragma unroll
        for (int p = 0; p < 4; ++p) {
            const int row  = p * 16 + (tid >> 4);   // 0..63
            const int col4 = (tid & 15) * 4;        // 0..60
            const f32x4 v = *(const f32x4*)&obuf[row * 68 + col4];
            __builtin_nontemporal_store(v,
                (f32x4*)(tb + (size_t)row * IN_F + it * 64 + col4));
        }
        __syncthreads();                 // obuf reads done before next overwrite
    }
}

// ---------------------------------------------------------------------------
extern "C" void kernel_launch(void* const* d_in, const int* in_sizes, int n_in,
                              void* d_out, int out_size, void* d_ws, size_t ws_size,
                              hipStream_t stream) {
    const float* x = (const float*)d_in[0];   // (T, B, IN) binary spikes
    const float* W = (const float*)d_in[1];   // (OUT, IN)

    float* out   = (float*)d_out;
    float* S_out = out;                                            // (T, B, OUT)
    float* Uh    = out + (size_t)T_STEPS * B_N * OUT_F;            // (2T, B, OUT)
    float* trace = Uh + (size_t)2 * T_STEPS * B_N * OUT_F;         // (B, OUT, IN)

    // ws layout: Wt (1 MB) | Xbits (1 MB). ws >= 3.2 MB proven (R9/R10 ran).
    float*        Wt    = (float*)d_ws;
    unsigned int* Xbits = (unsigned int*)((char*)d_ws + (size_t)IN_F * OUT_F * 4);

    // C (f64, 52 MB) reuses the trace region of d_out; trace_bits3 reads only
    // Uh + Xbits and runs last, so no hazard.
    double* C = (double*)trace;

    transposeW<<<256, 256, 0, stream>>>(W, Wt);
    syn_plus<<<512 + T_STEPS * B_N, 256, 0, stream>>>(x, Wt, C, Xbits);
    lif_pointwise<<<B_N * OUT_F / 256, 256, 0, stream>>>(C, S_out, Uh);
    trace_bits3<<<1024, 256, 0, stream>>>(Uh, Xbits, trace);
}